// Round 2
// baseline (908.064 us; speedup 1.0000x reference)
//
#include <hip/hip_runtime.h>

#define EMB 128

// 26 valid (ok, di, ol) message combos: deltas = {1,2,-1,-2}, ol = ok+delta in [0,8)
static constexpr int OKv[26] = {0,0,1,1,1,2,2,2,2,3,3,3,3,4,4,4,4,5,5,5,5,6,6,6,7,7};
static constexpr int DIv[26] = {0,1,0,1,2,0,1,2,3,0,1,2,3,0,1,2,3,0,1,2,3,0,2,3,2,3};
static constexpr int OLv[26] = {1,2,2,3,0,3,4,1,0,4,5,2,1,5,6,3,2,6,7,4,3,7,5,4,6,5};

__device__ __forceinline__ float4 ld4(const float* p) { return *(const float4*)p; }

__device__ __forceinline__ void fma_s4(float4& acc, float s, const float4& b) {
  acc.x = fmaf(s, b.x, acc.x); acc.y = fmaf(s, b.y, acc.y);
  acc.z = fmaf(s, b.z, acc.z); acc.w = fmaf(s, b.w, acc.w);
}
__device__ __forceinline__ void fma_44(float4& acc, const float4& a, const float4& b) {
  acc.x = fmaf(a.x, b.x, acc.x); acc.y = fmaf(a.y, b.y, acc.y);
  acc.z = fmaf(a.z, b.z, acc.z); acc.w = fmaf(a.w, b.w, acc.w);
}

// out[g] = b_pred[0], g < 64
__global__ void out_init_kernel(float* __restrict__ out, const float* __restrict__ b_pred) {
  out[threadIdx.x] = b_pred[0];
}

// lin[n][e] = sum_f emb_x[x[n]][f] * w_ti[f][e] + b_ti[e]
__global__ void lin_kernel(const int* __restrict__ x, const float* __restrict__ emb_x,
                           const float* __restrict__ w_ti, const float* __restrict__ b_ti,
                           float* __restrict__ lin) {
  const int n = blockIdx.x;
  const int e = threadIdx.x;
  const float* xr = emb_x + x[n] * EMB;
  float a0 = b_ti[e], a1 = 0.f, a2 = 0.f, a3 = 0.f;
  #pragma unroll 4
  for (int f = 0; f < EMB; f += 4) {
    a0 = fmaf(xr[f + 0], w_ti[(f + 0) * EMB + e], a0);
    a1 = fmaf(xr[f + 1], w_ti[(f + 1) * EMB + e], a1);
    a2 = fmaf(xr[f + 2], w_ti[(f + 2) * EMB + e], a2);
    a3 = fmaf(xr[f + 3], w_ti[(f + 3) * EMB + e], a3);
  }
  lin[n * EMB + e] = (a0 + a1) + (a2 + a3);
}

// One wave handles 2 pairs (half-wave each); lane owns 4 channels (c0..c0+3).
// Whole 5-layer message-pass + matmul pipeline is register/LDS resident per pair.
// amdgpu_waves_per_eu(4,4): pin exactly 4 waves/EU -> VGPR budget 128, NO SPILLS.
// (launch_bounds(256,4) alone let the backend pick a 64-VGPR budget and spill
//  ~450 B/thread -> 476 MB WRITE_SIZE, the round-1 bottleneck.)
__global__ __launch_bounds__(256)
__attribute__((amdgpu_waves_per_eu(4, 4)))
void i2gnn_main(
    const int* __restrict__ x,
    const int* __restrict__ edge_attr,
    const int* __restrict__ tuplefeat,
    const float* __restrict__ emb_x,
    const float* __restrict__ emb_tf,
    const float* __restrict__ emb_ea,
    const float* __restrict__ lin,
    const float* __restrict__ w_conv,
    const float* __restrict__ b_conv,
    const float* __restrict__ w_pred,
    float* __restrict__ out)
{
  __shared__ float4 ea_lds[16 * 32];         // 16 rows x 128 ch = 8 KB
  __shared__ float4 agg_lds[4][2][8][32];    // wave, half, k, f4  = 32 KB

  const int tid = threadIdx.x;
  // stage emb_ea (16x128 floats) into LDS once
  for (int t = tid; t < 512; t += 256) ea_lds[t] = ((const float4*)emb_ea)[t];
  __syncthreads();

  const int wave = tid >> 6;
  const int lane = tid & 63;
  const int h    = lane >> 5;     // which pair of this wave
  const int l5   = lane & 31;     // lane within half-wave
  const int c0   = l5 << 2;       // first of 4 owned channels

  const int p     = ((blockIdx.x << 2) + wave) * 2 + h;  // pair id, [0, 32768)
  const int i     = p >> 3;                              // root node
  const int jj    = p & 7;                               // window slot
  const int ibase = i & ~63;
  const int io    = i & 63;
  const int jnode = ibase + ((io + jj) & 63);            // tupleid1 of this pair
  const int g     = i >> 6;                              // graph id

  // Pack the 26 per-pair edge attrs (4 bits each, values < 16)
  unsigned pk[4] = {0u, 0u, 0u, 0u};
  #pragma unroll
  for (int m = 0; m < 26; ++m) {
    const int kg = ibase + ((io + OKv[m]) & 63);             // k_glob
    const unsigned attr = (unsigned)edge_attr[(kg << 2) + DIv[m]];
    pk[m >> 3] |= attr << ((m & 7) * 4);
  }

  // tupleinit: Xv[k] = xe[i] * lin[jnode] * tf[tuple]
  const float4 xe = ld4(emb_x + x[i] * EMB + c0);
  const float4 lj = ld4(lin + jnode * EMB + c0);
  float4 Xv[8];
  #pragma unroll
  for (int k = 0; k < 8; ++k) {
    const int t = (p << 3) + k;
    const int2 tf2 = *(const int2*)(tuplefeat + (t << 1));
    const int row = (l5 < 16) ? tf2.x : tf2.y;   // ch<64 -> feat0 row, else feat1 row
    const float4 tf = ld4(emb_tf + (row << 6) + (c0 & 63));
    Xv[k] = make_float4(xe.x * lj.x * tf.x, xe.y * lj.y * tf.y,
                        xe.z * lj.z * tf.z, xe.w * lj.w * tf.w);
  }

  float4* myagg = &agg_lds[wave][h][0][0];

  for (int l = 0; l < 5; ++l) {
    // ---- message pass (within-pair, 26 fixed edges) ----
    float4 acc[8];
    #pragma unroll
    for (int k = 0; k < 8; ++k) acc[k] = make_float4(0.f, 0.f, 0.f, 0.f);
    #pragma unroll
    for (int m = 0; m < 26; ++m) {
      const unsigned attr = (pk[m >> 3] >> ((m & 7) * 4)) & 15u;
      const float4 ea = ea_lds[(attr << 5) + l5];
      fma_44(acc[OKv[m]], Xv[OLv[m]], ea);
    }
    // stash agg to LDS so all lanes of this half-wave can see all 128 f-channels
    #pragma unroll
    for (int k = 0; k < 8; ++k) myagg[(k << 5) + l5] = acc[k];

    // ---- matmul: o[k][c] = sum_f agg[k][f] * w[f][c] ----
    const float* wl = w_conv + l * (EMB * EMB);
    float4 o[8];
    #pragma unroll
    for (int k = 0; k < 8; ++k) o[k] = make_float4(0.f, 0.f, 0.f, 0.f);
    for (int f2 = 0; f2 < 32; ++f2) {
      const float* wr = wl + (f2 << 9) + c0;   // rows 4*f2 .. 4*f2+3
      const float4 w0 = ld4(wr);
      const float4 w1 = ld4(wr + 128);
      const float4 w2 = ld4(wr + 256);
      const float4 w3 = ld4(wr + 384);
      #pragma unroll
      for (int k = 0; k < 8; ++k) {
        const float4 a = myagg[(k << 5) + f2];  // broadcast within half-wave
        fma_s4(o[k], a.x, w0);
        fma_s4(o[k], a.y, w1);
        fma_s4(o[k], a.z, w2);
        fma_s4(o[k], a.w, w3);
      }
    }
    const float4 bc = ld4(b_conv + l * EMB + c0);
    #pragma unroll
    for (int k = 0; k < 8; ++k) {
      Xv[k].x += fmaxf(o[k].x + bc.x, 0.f);
      Xv[k].y += fmaxf(o[k].y + bc.y, 0.f);
      Xv[k].z += fmaxf(o[k].z + bc.z, 0.f);
      Xv[k].w += fmaxf(o[k].w + bc.w, 0.f);
    }
  }

  // ---- pooling: max over k, then dot with w_pred, then per-graph sum ----
  float4 pv = Xv[0];
  #pragma unroll
  for (int k = 1; k < 8; ++k) {
    pv.x = fmaxf(pv.x, Xv[k].x);
    pv.y = fmaxf(pv.y, Xv[k].y);
    pv.z = fmaxf(pv.z, Xv[k].z);
    pv.w = fmaxf(pv.w, Xv[k].w);
  }
  const float4 wp = ld4(w_pred + c0);
  float s = pv.x * wp.x + pv.y * wp.y + pv.z * wp.z + pv.w * wp.w;
  // reduce over the 32 lanes of this half-wave (xor offsets < 32 stay in-half)
  #pragma unroll
  for (int off = 16; off; off >>= 1) s += __shfl_xor(s, off, 64);
  if (l5 == 0) atomicAdd(out + g, s);
}

extern "C" void kernel_launch(void* const* d_in, const int* in_sizes, int n_in,
                              void* d_out, int out_size, void* d_ws, size_t ws_size,
                              hipStream_t stream) {
  const int*   x         = (const int*)d_in[0];
  const int*   edge_attr = (const int*)d_in[1];
  const int*   tuplefeat = (const int*)d_in[2];
  const float* emb_x     = (const float*)d_in[12];
  const float* emb_ea    = (const float*)d_in[13];
  const float* emb_tf    = (const float*)d_in[14];
  const float* w_ti      = (const float*)d_in[15];
  const float* b_ti      = (const float*)d_in[16];
  const float* w_conv    = (const float*)d_in[17];
  const float* b_conv    = (const float*)d_in[18];
  const float* w_pred    = (const float*)d_in[19];
  const float* b_pred    = (const float*)d_in[20];
  float* out = (float*)d_out;
  float* lin = (float*)d_ws;   // 4096 x 128 fp32 = 2 MB scratch

  hipLaunchKernelGGL(out_init_kernel, dim3(1), dim3(64), 0, stream, out, b_pred);
  hipLaunchKernelGGL(lin_kernel, dim3(4096), dim3(EMB), 0, stream, x, emb_x, w_ti, b_ti, lin);
  hipLaunchKernelGGL(i2gnn_main, dim3(4096), dim3(256), 0, stream,
                     x, edge_attr, tuplefeat, emb_x, emb_tf, emb_ea, lin,
                     w_conv, b_conv, w_pred, out);
}

// Round 3
// 825.005 us; speedup vs baseline: 1.1007x; 1.1007x over previous
//
#include <hip/hip_runtime.h>

#define EMB 128

// 26 valid (ok, di, ol) message combos: deltas = {1,2,-1,-2}, ol = ok+delta in [0,8)
static constexpr int OKv[26] = {0,0,1,1,1,2,2,2,2,3,3,3,3,4,4,4,4,5,5,5,5,6,6,6,7,7};
static constexpr int DIv[26] = {0,1,0,1,2,0,1,2,3,0,1,2,3,0,1,2,3,0,1,2,3,0,2,3,2,3};
static constexpr int OLv[26] = {1,2,2,3,0,3,4,1,0,4,5,2,1,5,6,3,2,6,7,4,3,7,5,4,6,5};

__device__ __forceinline__ float2 ld2(const float* p) { return *(const float2*)p; }
__device__ __forceinline__ float4 ld4(const float* p) { return *(const float4*)p; }

// out[g] = b_pred[0], g < 64
__global__ void out_init_kernel(float* __restrict__ out, const float* __restrict__ b_pred) {
  out[threadIdx.x] = b_pred[0];
}

// lin[n][e] = sum_f emb_x[x[n]][f] * w_ti[f][e] + b_ti[e]
__global__ void lin_kernel(const int* __restrict__ x, const float* __restrict__ emb_x,
                           const float* __restrict__ w_ti, const float* __restrict__ b_ti,
                           float* __restrict__ lin) {
  const int n = blockIdx.x;
  const int e = threadIdx.x;
  const float* xr = emb_x + x[n] * EMB;
  float a0 = b_ti[e], a1 = 0.f, a2 = 0.f, a3 = 0.f;
  #pragma unroll 4
  for (int f = 0; f < EMB; f += 4) {
    a0 = fmaf(xr[f + 0], w_ti[(f + 0) * EMB + e], a0);
    a1 = fmaf(xr[f + 1], w_ti[(f + 1) * EMB + e], a1);
    a2 = fmaf(xr[f + 2], w_ti[(f + 2) * EMB + e], a2);
    a3 = fmaf(xr[f + 3], w_ti[(f + 3) * EMB + e], a3);
  }
  lin[n * EMB + e] = (a0 + a1) + (a2 + a3);
}

// One FULL wave per pair; lane owns 2 channels (c0, c0+1).
// Live state ~55 VGPRs -> fits the compiler's 64-VGPR budget with NO spills.
// (Round 1/2: half-wave/4ch layout needed ~90 live regs at a 64-reg budget ->
//  476 MB scratch spill traffic, the entire perf gap vs the 273 us VALU floor.)
__global__ __launch_bounds__(256)
void i2gnn_main(
    const int* __restrict__ x,
    const int* __restrict__ edge_attr,
    const int* __restrict__ tuplefeat,
    const float* __restrict__ emb_x,
    const float* __restrict__ emb_tf,
    const float* __restrict__ emb_ea,
    const float* __restrict__ lin,
    const float* __restrict__ w_conv,
    const float* __restrict__ b_conv,
    const float* __restrict__ w_pred,
    float* __restrict__ out)
{
  __shared__ float2 ea_lds[16 * 64];     // 16 attr rows x 128 ch = 8 KB
  __shared__ float2 agg_lds[4][8][64];   // wave, k, lane(2ch)    = 16 KB

  const int tid = threadIdx.x;
  // stage emb_ea (16x128 floats = 1024 float2) into LDS once
  for (int t = tid; t < 1024; t += 256) ea_lds[t] = ((const float2*)emb_ea)[t];
  __syncthreads();

  const int wave = tid >> 6;
  const int lane = tid & 63;
  const int c0   = lane << 1;          // first of 2 owned channels

  const int p     = (blockIdx.x << 2) + wave;   // pair id, [0, 32768)
  const int i     = p >> 3;                     // root node
  const int jj    = p & 7;                      // window slot
  const int ibase = i & ~63;
  const int io    = i & 63;
  const int jnode = ibase + ((io + jj) & 63);   // tupleid1 of this pair
  const int g     = i >> 6;                     // graph id

  // Pack the 26 per-pair edge attrs (4 bits each, values < 16)
  unsigned pk[4] = {0u, 0u, 0u, 0u};
  #pragma unroll
  for (int m = 0; m < 26; ++m) {
    const int kg = ibase + ((io + OKv[m]) & 63);            // k_glob
    const unsigned attr = (unsigned)edge_attr[(kg << 2) + DIv[m]];
    pk[m >> 3] |= attr << ((m & 7) * 4);
  }

  // tupleinit: Xv[k] = xe[i] * lin[jnode] * tf[tuple]
  const float2 xe = ld2(emb_x + x[i] * EMB + c0);
  const float2 lj = ld2(lin + jnode * EMB + c0);
  float2 Xv[8];
  #pragma unroll
  for (int k = 0; k < 8; ++k) {
    const int t = (p << 3) + k;
    const int2 tf2 = *(const int2*)(tuplefeat + (t << 1));
    const int row = (lane < 32) ? tf2.x : tf2.y;  // ch<64 -> feat0 row, else feat1
    const float2 tf = ld2(emb_tf + (row << 6) + (c0 & 63));
    Xv[k] = make_float2(xe.x * lj.x * tf.x, xe.y * lj.y * tf.y);
  }

  float2* myagg = &agg_lds[wave][0][0];          // [8][64] float2
  const float4* aggv = (const float4*)myagg;     // [8][32] float4 (4 ch per entry)

  for (int l = 0; l < 5; ++l) {
    // ---- message pass (within-pair, 26 fixed edges) ----
    float2 acc[8];
    #pragma unroll
    for (int k = 0; k < 8; ++k) acc[k] = make_float2(0.f, 0.f);
    #pragma unroll
    for (int m = 0; m < 26; ++m) {
      const unsigned attr = (pk[m >> 3] >> ((m & 7) * 4)) & 15u;
      const float2 ea = ea_lds[(attr << 6) + lane];
      acc[OKv[m]].x = fmaf(Xv[OLv[m]].x, ea.x, acc[OKv[m]].x);
      acc[OKv[m]].y = fmaf(Xv[OLv[m]].y, ea.y, acc[OKv[m]].y);
    }
    // stash agg to LDS: this wave's lanes collectively hold all 128 f-channels
    #pragma unroll
    for (int k = 0; k < 8; ++k) myagg[(k << 6) + lane] = acc[k];
    // within-wave LDS RAW: compiler inserts lgkmcnt wait; no barrier needed

    // ---- matmul: o[k][c] = sum_f agg[k][f] * w[f][c] ----
    const float* wl = w_conv + l * (EMB * EMB);
    float2 o[8];
    #pragma unroll
    for (int k = 0; k < 8; ++k) o[k] = make_float2(0.f, 0.f);
    for (int f2 = 0; f2 < 32; ++f2) {
      const float* wr = wl + (f2 << 9) + c0;     // rows 4*f2 .. 4*f2+3, cols c0..c0+1
      const float2 w0 = ld2(wr);
      const float2 w1 = ld2(wr + 128);
      const float2 w2 = ld2(wr + 256);
      const float2 w3 = ld2(wr + 384);
      #pragma unroll
      for (int k = 0; k < 8; ++k) {
        const float4 a = aggv[(k << 5) + f2];    // wave-uniform addr -> LDS broadcast
        o[k].x = fmaf(a.x, w0.x, o[k].x); o[k].y = fmaf(a.x, w0.y, o[k].y);
        o[k].x = fmaf(a.y, w1.x, o[k].x); o[k].y = fmaf(a.y, w1.y, o[k].y);
        o[k].x = fmaf(a.z, w2.x, o[k].x); o[k].y = fmaf(a.z, w2.y, o[k].y);
        o[k].x = fmaf(a.w, w3.x, o[k].x); o[k].y = fmaf(a.w, w3.y, o[k].y);
      }
    }
    const float2 bc = ld2(b_conv + l * EMB + c0);
    #pragma unroll
    for (int k = 0; k < 8; ++k) {
      Xv[k].x += fmaxf(o[k].x + bc.x, 0.f);
      Xv[k].y += fmaxf(o[k].y + bc.y, 0.f);
    }
  }

  // ---- pooling: max over k, dot with w_pred, per-graph atomic sum ----
  float2 pv = Xv[0];
  #pragma unroll
  for (int k = 1; k < 8; ++k) {
    pv.x = fmaxf(pv.x, Xv[k].x);
    pv.y = fmaxf(pv.y, Xv[k].y);
  }
  const float2 wp = ld2(w_pred + c0);
  float s = pv.x * wp.x + pv.y * wp.y;
  #pragma unroll
  for (int off = 32; off; off >>= 1) s += __shfl_xor(s, off, 64);
  if (lane == 0) atomicAdd(out + g, s);
}

extern "C" void kernel_launch(void* const* d_in, const int* in_sizes, int n_in,
                              void* d_out, int out_size, void* d_ws, size_t ws_size,
                              hipStream_t stream) {
  const int*   x         = (const int*)d_in[0];
  const int*   edge_attr = (const int*)d_in[1];
  const int*   tuplefeat = (const int*)d_in[2];
  const float* emb_x     = (const float*)d_in[12];
  const float* emb_ea    = (const float*)d_in[13];
  const float* emb_tf    = (const float*)d_in[14];
  const float* w_ti      = (const float*)d_in[15];
  const float* b_ti      = (const float*)d_in[16];
  const float* w_conv    = (const float*)d_in[17];
  const float* b_conv    = (const float*)d_in[18];
  const float* w_pred    = (const float*)d_in[19];
  const float* b_pred    = (const float*)d_in[20];
  float* out = (float*)d_out;
  float* lin = (float*)d_ws;   // 4096 x 128 fp32 = 2 MB scratch

  hipLaunchKernelGGL(out_init_kernel, dim3(1), dim3(64), 0, stream, out, b_pred);
  hipLaunchKernelGGL(lin_kernel, dim3(4096), dim3(EMB), 0, stream, x, emb_x, w_ti, b_ti, lin);
  hipLaunchKernelGGL(i2gnn_main, dim3(8192), dim3(256), 0, stream,
                     x, edge_attr, tuplefeat, emb_x, emb_tf, emb_ea, lin,
                     w_conv, b_conv, w_pred, out);
}

// Round 4
// 522.883 us; speedup vs baseline: 1.7366x; 1.5778x over previous
//
#include <hip/hip_runtime.h>

#define EMB 128

typedef __attribute__((ext_vector_type(8))) short short8;   // 8 bf16 (4 VGPRs)
typedef __attribute__((ext_vector_type(4))) float floatx4;  // MFMA C/D

// 26 valid (ok, di, ol) message combos: deltas = {1,2,-1,-2}, ol = ok+delta in [0,8)
static constexpr int OKv[26] = {0,0,1,1,1,2,2,2,2,3,3,3,3,4,4,4,4,5,5,5,5,6,6,6,7,7};
static constexpr int DIv[26] = {0,1,0,1,2,0,1,2,3,0,1,2,3,0,1,2,3,0,1,2,3,0,2,3,2,3};
static constexpr int OLv[26] = {1,2,2,3,0,3,4,1,0,4,5,2,1,5,6,3,2,6,7,4,3,7,5,4,6,5};

__device__ __forceinline__ float4 ld4(const float* p) { return *(const float4*)p; }

// round-to-nearest-even bf16 bits of x, kept in the TOP 16 bits (low 16 zero)
__device__ __forceinline__ unsigned bf16_rne_hi(float x) {
  unsigned u = __float_as_uint(x);
  return (u + 0x7FFFu + ((u >> 16) & 1u)) & 0xFFFF0000u;
}
// bf16(x) as a float (for computing the lo residual exactly)
__device__ __forceinline__ float bf16hi_f(float x) {
  return __uint_as_float(bf16_rne_hi(x));
}
// pack bf16(a) into low half, bf16(b) into high half
__device__ __forceinline__ unsigned pk2bf(float a, float b) {
  return (bf16_rne_hi(a) >> 16) | bf16_rne_hi(b);
}

union FragU { unsigned u[4]; uint4 q; short8 v; };

// out[g] = b_pred[0], g < 64
__global__ void out_init_kernel(float* __restrict__ out, const float* __restrict__ b_pred) {
  out[threadIdx.x] = b_pred[0];
}

// lin[n][e] = sum_f emb_x[x[n]][f] * w_ti[f][e] + b_ti[e]
__global__ void lin_kernel(const int* __restrict__ x, const float* __restrict__ emb_x,
                           const float* __restrict__ w_ti, const float* __restrict__ b_ti,
                           float* __restrict__ lin) {
  const int n = blockIdx.x;
  const int e = threadIdx.x;
  const float* xr = emb_x + x[n] * EMB;
  float a0 = b_ti[e], a1 = 0.f, a2 = 0.f, a3 = 0.f;
  #pragma unroll 4
  for (int f = 0; f < EMB; f += 4) {
    a0 = fmaf(xr[f + 0], w_ti[(f + 0) * EMB + e], a0);
    a1 = fmaf(xr[f + 1], w_ti[(f + 1) * EMB + e], a1);
    a2 = fmaf(xr[f + 2], w_ti[(f + 2) * EMB + e], a2);
    a3 = fmaf(xr[f + 3], w_ti[(f + 3) * EMB + e], a3);
  }
  lin[n * EMB + e] = (a0 + a1) + (a2 + a3);
}

// Pre-pack w_conv into MFMA B-fragment order, split into bf16 hi/lo planes.
// frag(l,t,u,pass): B[k][n] for 16x16x32: n = lane&15, k = (lane>>4)*8 + j.
// Stored as uint4 per (frag, lane): 8 bf16, element j in word j>>1 (low/high).
__global__ void wfrag_kernel(const float* __restrict__ w_conv, uint4* __restrict__ wfrag) {
  const int id   = blockIdx.x * 256 + threadIdx.x;   // 320 frags * 64 lanes = 20480
  const int lane = id & 63;
  const int f    = id >> 6;
  const int pass = f & 1;           // 0 = hi, 1 = lo
  const int u    = (f >> 1) & 7;    // N-tile
  const int t    = (f >> 4) & 3;    // K-tile
  const int l    = f >> 6;          // layer
  const int q    = lane >> 4, n = lane & 15;
  unsigned w[4] = {0u, 0u, 0u, 0u};
  #pragma unroll
  for (int j = 0; j < 8; ++j) {
    const int ff = t * 32 + q * 8 + j;          // K index (input channel)
    const int c  = u * 16 + n;                  // N index (output channel)
    float val = w_conv[l * (EMB * EMB) + ff * EMB + c];
    if (pass) val = val - bf16hi_f(val);        // lo residual
    const unsigned b = bf16_rne_hi(val);        // rounded bf16 in top 16
    w[j >> 1] |= (j & 1) ? b : (b >> 16);
  }
  wfrag[id] = make_uint4(w[0], w[1], w[2], w[3]);
}

// Block = 4 waves = root node i's 8 pairs. Wave = 2 pairs (M=16 rows).
// Half-wave owns one pair in flat layout (lane: 4 channels); per layer:
//   VALU message pass -> agg to LDS -> MFMA (bf16 hi/lo 3-term split)
//   with W streamed as pre-packed B-fragments -> epilogue back via LDS.
__global__ __launch_bounds__(256) void i2gnn_mfma(
    const int* __restrict__ x,
    const int* __restrict__ edge_attr,
    const int* __restrict__ tuplefeat,
    const float* __restrict__ emb_x,
    const float* __restrict__ emb_tf,
    const float* __restrict__ emb_ea,
    const float* __restrict__ lin,
    const float* __restrict__ b_conv,
    const float* __restrict__ w_pred,
    const uint4* __restrict__ wfrag,
    float* __restrict__ out)
{
  __shared__ float ea_s[16 * EMB];        // emb_ea verbatim, 8 KB
  __shared__ float aggT[4][16 * 140];     // per-wave 16 rows x 128 ch, stride 140 (pad) = 35 KB

  const int tid = threadIdx.x;
  for (int tt = tid; tt < 1024; tt += 256)
    ((float2*)ea_s)[tt] = ((const float2*)emb_ea)[tt];
  __syncthreads();

  const int wv = tid >> 6, lane = tid & 63;
  const int h = lane >> 5, l5 = lane & 31;
  const int c0 = l5 << 2;                 // 4 owned channels (flat layout)
  const int m16 = lane & 15, q = lane >> 4;

  const int i = blockIdx.x;               // root node, one per block
  const int jj = wv * 2 + h;              // window slot of this half-wave's pair
  const int ibase = i & ~63, io = i & 63;
  const int jnode = ibase + ((io + jj) & 63);
  const int g = i >> 6;
  const int p = i * 8 + jj;

  // Pack the 26 edge attrs (4 bits each) — function of i only (same for all 8 pairs)
  unsigned pk[4] = {0u, 0u, 0u, 0u};
  #pragma unroll
  for (int m = 0; m < 26; ++m) {
    const int kg = ibase + ((io + OKv[m]) & 63);
    const unsigned a = (unsigned)edge_attr[(kg << 2) + DIv[m]];
    pk[m >> 3] |= a << ((m & 7) * 4);
  }

  // tupleinit: X[k] = xe[i] * lin[jnode] * tf[tuple]   (flat: half-wave = pair)
  const float4 xe = ld4(emb_x + x[i] * EMB + c0);
  const float4 lj = ld4(lin + jnode * EMB + c0);
  float4 X[8];
  #pragma unroll
  for (int k = 0; k < 8; ++k) {
    const int t = (p << 3) + k;
    const int2 tf2 = *(const int2*)(tuplefeat + (t << 1));
    const int row = (l5 < 16) ? tf2.x : tf2.y;
    const float4 tf = ld4(emb_tf + (row << 6) + (c0 & 63));
    X[k] = make_float4(xe.x * lj.x * tf.x, xe.y * lj.y * tf.y,
                       xe.z * lj.z * tf.z, xe.w * lj.w * tf.w);
  }

  float* myT = aggT[wv];

  for (int l = 0; l < 5; ++l) {
    // ---- message pass (fp32 VALU, within-pair) ----
    float4 acc[8];
    #pragma unroll
    for (int k = 0; k < 8; ++k) acc[k] = make_float4(0.f, 0.f, 0.f, 0.f);
    #pragma unroll
    for (int m = 0; m < 26; ++m) {
      const unsigned attr = (pk[m >> 3] >> ((m & 7) * 4)) & 15u;
      const float4 ea = ld4(ea_s + attr * EMB + c0);
      acc[OKv[m]].x = fmaf(X[OLv[m]].x, ea.x, acc[OKv[m]].x);
      acc[OKv[m]].y = fmaf(X[OLv[m]].y, ea.y, acc[OKv[m]].y);
      acc[OKv[m]].z = fmaf(X[OLv[m]].z, ea.z, acc[OKv[m]].z);
      acc[OKv[m]].w = fmaf(X[OLv[m]].w, ea.w, acc[OKv[m]].w);
    }
    // ---- agg -> LDS rows (row = h*8+k), then read as MFMA A-fragments ----
    #pragma unroll
    for (int k = 0; k < 8; ++k)
      *(float4*)(myT + (h * 8 + k) * 140 + c0) = acc[k];

    floatx4 C[8];
    #pragma unroll
    for (int u = 0; u < 8; ++u) C[u] = (floatx4){0.f, 0.f, 0.f, 0.f};

    #pragma unroll
    for (int t = 0; t < 4; ++t) {
      // A-fragment: A[m=lane&15][k = q*8 + j], f = t*32 + q*8 + j
      const float* ap = myT + m16 * 140 + t * 32 + q * 8;
      const float4 f0 = *(const float4*)(ap);
      const float4 f1 = *(const float4*)(ap + 4);
      FragU Ahi, Alo;
      Ahi.u[0] = pk2bf(f0.x, f0.y); Ahi.u[1] = pk2bf(f0.z, f0.w);
      Ahi.u[2] = pk2bf(f1.x, f1.y); Ahi.u[3] = pk2bf(f1.z, f1.w);
      Alo.u[0] = pk2bf(f0.x - bf16hi_f(f0.x), f0.y - bf16hi_f(f0.y));
      Alo.u[1] = pk2bf(f0.z - bf16hi_f(f0.z), f0.w - bf16hi_f(f0.w));
      Alo.u[2] = pk2bf(f1.x - bf16hi_f(f1.x), f1.y - bf16hi_f(f1.y));
      Alo.u[3] = pk2bf(f1.z - bf16hi_f(f1.z), f1.w - bf16hi_f(f1.w));
      #pragma unroll
      for (int u = 0; u < 8; ++u) {
        const int base = (((l * 4 + t) * 8 + u) * 2) << 6;
        FragU Bhi, Blo;
        Bhi.q = wfrag[base + lane];
        Blo.q = wfrag[base + 64 + lane];
        C[u] = __builtin_amdgcn_mfma_f32_16x16x32_bf16(Ahi.v, Bhi.v, C[u], 0, 0, 0);
        C[u] = __builtin_amdgcn_mfma_f32_16x16x32_bf16(Alo.v, Bhi.v, C[u], 0, 0, 0);
        C[u] = __builtin_amdgcn_mfma_f32_16x16x32_bf16(Ahi.v, Blo.v, C[u], 0, 0, 0);
      }
    }

    // ---- o (C-layout: row = q*4+r, ch = u*16+m16) -> LDS -> flat epilogue ----
    #pragma unroll
    for (int u = 0; u < 8; ++u) {
      #pragma unroll
      for (int r = 0; r < 4; ++r)
        myT[(q * 4 + r) * 140 + u * 16 + m16] = C[u][r];
    }
    const float4 b4 = ld4(b_conv + l * EMB + c0);
    #pragma unroll
    for (int k = 0; k < 8; ++k) {
      const float4 o = *(const float4*)(myT + (h * 8 + k) * 140 + c0);
      X[k].x += fmaxf(o.x + b4.x, 0.f);
      X[k].y += fmaxf(o.y + b4.y, 0.f);
      X[k].z += fmaxf(o.z + b4.z, 0.f);
      X[k].w += fmaxf(o.w + b4.w, 0.f);
    }
  }

  // ---- pooling: max over k, dot w_pred, per-graph atomic sum ----
  float4 pv = X[0];
  #pragma unroll
  for (int k = 1; k < 8; ++k) {
    pv.x = fmaxf(pv.x, X[k].x);
    pv.y = fmaxf(pv.y, X[k].y);
    pv.z = fmaxf(pv.z, X[k].z);
    pv.w = fmaxf(pv.w, X[k].w);
  }
  const float4 wp = ld4(w_pred + c0);
  float s = pv.x * wp.x + pv.y * wp.y + pv.z * wp.z + pv.w * wp.w;
  #pragma unroll
  for (int off = 16; off; off >>= 1) s += __shfl_xor(s, off, 64);
  if (l5 == 0) atomicAdd(out + g, s);
}

extern "C" void kernel_launch(void* const* d_in, const int* in_sizes, int n_in,
                              void* d_out, int out_size, void* d_ws, size_t ws_size,
                              hipStream_t stream) {
  const int*   x         = (const int*)d_in[0];
  const int*   edge_attr = (const int*)d_in[1];
  const int*   tuplefeat = (const int*)d_in[2];
  const float* emb_x     = (const float*)d_in[12];
  const float* emb_ea    = (const float*)d_in[13];
  const float* emb_tf    = (const float*)d_in[14];
  const float* w_ti      = (const float*)d_in[15];
  const float* b_ti      = (const float*)d_in[16];
  const float* w_conv    = (const float*)d_in[17];
  const float* b_conv    = (const float*)d_in[18];
  const float* w_pred    = (const float*)d_in[19];
  const float* b_pred    = (const float*)d_in[20];
  float* out = (float*)d_out;
  float* lin = (float*)d_ws;                                   // 4096*128 fp32 = 2 MB
  uint4* wfrag = (uint4*)((char*)d_ws + 4096 * EMB * 4);       // 320 KB B-fragments

  hipLaunchKernelGGL(out_init_kernel, dim3(1), dim3(64), 0, stream, out, b_pred);
  hipLaunchKernelGGL(lin_kernel, dim3(4096), dim3(EMB), 0, stream, x, emb_x, w_ti, b_ti, lin);
  hipLaunchKernelGGL(wfrag_kernel, dim3(80), dim3(256), 0, stream, w_conv, wfrag);
  hipLaunchKernelGGL(i2gnn_mfma, dim3(4096), dim3(256), 0, stream,
                     x, edge_attr, tuplefeat, emb_x, emb_tf, emb_ea, lin,
                     b_conv, w_pred, wfrag, out);
}

// Round 5
// 332.825 us; speedup vs baseline: 2.7284x; 1.5710x over previous
//
#include <hip/hip_runtime.h>

#define EMB 128

typedef __attribute__((ext_vector_type(8))) short short8;   // 8 bf16 (4 VGPRs)
typedef __attribute__((ext_vector_type(4))) float floatx4;  // MFMA C/D

// 26 valid (ok, di, ol) message combos: deltas = {1,2,-1,-2}, ol = ok+delta in [0,8)
static constexpr int OKv[26] = {0,0,1,1,1,2,2,2,2,3,3,3,3,4,4,4,4,5,5,5,5,6,6,6,7,7};
static constexpr int DIv[26] = {0,1,0,1,2,0,1,2,3,0,1,2,3,0,1,2,3,0,1,2,3,0,2,3,2,3};
static constexpr int OLv[26] = {1,2,2,3,0,3,4,1,0,4,5,2,1,5,6,3,2,6,7,4,3,7,5,4,6,5};

__device__ __forceinline__ float4 ld4(const float* p) { return *(const float4*)p; }

// round-to-nearest-even bf16 bits of x, kept in the TOP 16 bits (low 16 zero)
__device__ __forceinline__ unsigned bf16_rne_hi(float x) {
  unsigned u = __float_as_uint(x);
  return (u + 0x7FFFu + ((u >> 16) & 1u)) & 0xFFFF0000u;
}
__device__ __forceinline__ float bf16hi_f(float x) {
  return __uint_as_float(bf16_rne_hi(x));
}

union FragU { unsigned u[4]; uint4 q; short8 v; };

// out[g] = b_pred[0], g < 64
__global__ void out_init_kernel(float* __restrict__ out, const float* __restrict__ b_pred) {
  out[threadIdx.x] = b_pred[0];
}

// lin32[v][e] = emb_x[v] @ w_ti + b_ti  — lin[node] = lin32[x[node]] (only 32 distinct)
__global__ void lin_kernel(const float* __restrict__ emb_x,
                           const float* __restrict__ w_ti, const float* __restrict__ b_ti,
                           float* __restrict__ lin32) {
  const int n = blockIdx.x;      // x-value 0..31
  const int e = threadIdx.x;
  const float* xr = emb_x + n * EMB;
  float a0 = b_ti[e], a1 = 0.f, a2 = 0.f, a3 = 0.f;
  #pragma unroll 4
  for (int f = 0; f < EMB; f += 4) {
    a0 = fmaf(xr[f + 0], w_ti[(f + 0) * EMB + e], a0);
    a1 = fmaf(xr[f + 1], w_ti[(f + 1) * EMB + e], a1);
    a2 = fmaf(xr[f + 2], w_ti[(f + 2) * EMB + e], a2);
    a3 = fmaf(xr[f + 3], w_ti[(f + 3) * EMB + e], a3);
  }
  lin32[n * EMB + e] = (a0 + a1) + (a2 + a3);
}

// Pre-pack w_conv into MFMA B-fragment order, split into bf16 hi/lo planes.
// frag(l,t,u,pass): B[k][n]: n = lane&15, k = (lane>>4)*8 + j. uint4/lane.
__global__ void wfrag_kernel(const float* __restrict__ w_conv, uint4* __restrict__ wfrag) {
  const int id   = blockIdx.x * 256 + threadIdx.x;   // 320 frags * 64 lanes
  const int lane = id & 63;
  const int f    = id >> 6;
  const int pass = f & 1;           // 0 = hi, 1 = lo
  const int u    = (f >> 1) & 7;    // N-tile
  const int t    = (f >> 4) & 3;    // K-tile
  const int l    = f >> 6;          // layer
  const int q    = lane >> 4, n = lane & 15;
  unsigned w[4] = {0u, 0u, 0u, 0u};
  #pragma unroll
  for (int j = 0; j < 8; ++j) {
    const int ff = t * 32 + q * 8 + j;
    const int c  = u * 16 + n;
    float val = w_conv[l * (EMB * EMB) + ff * EMB + c];
    if (pass) val = val - bf16hi_f(val);
    const unsigned b = bf16_rne_hi(val);
    w[j >> 1] |= (j & 1) ? b : (b >> 16);
  }
  wfrag[id] = make_uint4(w[0], w[1], w[2], w[3]);
}

// Block = root node i (8 pairs = 64 M-rows, row = wv*16 + 2k + h).
// Phase 1 (per layer): flat VALU message pass; pack acc to bf16 hi/lo planes
//   written DIRECTLY in A-fragment order to shared fragbuf (32 KB).
// Phase 2: wave w computes N-tiles u={2w,2w+1} for ALL 4 M-tiles (B-frags
//   loaded once per K-tile -> 4x less B traffic than R4).
// Phase 3: epilogue via fp32 scratch OVERLAYING fragbuf (XOR-16 col swizzle).
// LDS = 8 KB ea + 32 KB union = 40960 -> 4 blocks/CU (R4: 44 KB -> 3).
__global__ __launch_bounds__(256) void i2gnn_mfma(
    const int* __restrict__ x,
    const int* __restrict__ edge_attr,
    const int* __restrict__ tuplefeat,
    const float* __restrict__ emb_x,
    const float* __restrict__ emb_tf,
    const float* __restrict__ emb_ea,
    const float* __restrict__ lin32,
    const float* __restrict__ b_conv,
    const float* __restrict__ w_pred,
    const uint4* __restrict__ wfrag,
    float* __restrict__ out)
{
  __shared__ float ea_s[16 * EMB];     // 8 KB
  __shared__ uint4 fragbuf[2048];      // 32 KB: [plane][mtile][t][row16][q] granules
  float* epi = (float*)fragbuf;        // overlay: fp32 [64][128] after barrier

  const int tid = threadIdx.x;
  for (int tt = tid; tt < 1024; tt += 256)
    ((float2*)ea_s)[tt] = ((const float2*)emb_ea)[tt];

  const int wv = tid >> 6, lane = tid & 63;
  const int h = lane >> 5, l5 = lane & 31;
  const int c0 = l5 << 2;              // 4 owned channels (flat layout)
  const int m16 = lane & 15, q2 = lane >> 4;
  const int tq = l5 >> 3, qq = (l5 >> 1) & 3, pp = l5 & 1;  // A-write coords

  const int i = blockIdx.x;
  const int jj = wv * 2 + h;           // this half-wave's pair slot
  const int ibase = i & ~63, io = i & 63;
  const int jnode = ibase + ((io + jj) & 63);
  const int g = i >> 6;
  const int p = i * 8 + jj;

  // 26 edge attrs (4 bits each) — function of i only
  unsigned pk[4] = {0u, 0u, 0u, 0u};
  #pragma unroll
  for (int m = 0; m < 26; ++m) {
    const int kg = ibase + ((io + OKv[m]) & 63);
    const unsigned a = (unsigned)edge_attr[(kg << 2) + DIv[m]];
    pk[m >> 3] |= a << ((m & 7) * 4);
  }

  // tupleinit: X[k] = xe[i] * lin32[x[jnode]] * tf[tuple]
  const float4 xe = ld4(emb_x + x[i] * EMB + c0);
  const float4 lj = ld4(lin32 + x[jnode] * EMB + c0);
  float4 X[8];
  #pragma unroll
  for (int k = 0; k < 8; ++k) {
    const int t = (p << 3) + k;
    const int2 tf2 = *(const int2*)(tuplefeat + (t << 1));
    const int row = (l5 < 16) ? tf2.x : tf2.y;
    const float4 tf = ld4(emb_tf + (row << 6) + (c0 & 63));
    X[k] = make_float4(xe.x * lj.x * tf.x, xe.y * lj.y * tf.y,
                       xe.z * lj.z * tf.z, xe.w * lj.w * tf.w);
  }
  __syncthreads();   // ea_s ready; fragbuf about to be written

  const int u0 = wv * 2;
  uint2* f2 = (uint2*)fragbuf;

  for (int l = 0; l < 5; ++l) {
    // ---- message pass (fp32 VALU, within-pair) ----
    float4 acc[8];
    #pragma unroll
    for (int k = 0; k < 8; ++k) acc[k] = make_float4(0.f, 0.f, 0.f, 0.f);
    #pragma unroll
    for (int m = 0; m < 26; ++m) {
      const unsigned attr = (pk[m >> 3] >> ((m & 7) * 4)) & 15u;
      const float4 ea = ld4(ea_s + attr * EMB + c0);
      acc[OKv[m]].x = fmaf(X[OLv[m]].x, ea.x, acc[OKv[m]].x);
      acc[OKv[m]].y = fmaf(X[OLv[m]].y, ea.y, acc[OKv[m]].y);
      acc[OKv[m]].z = fmaf(X[OLv[m]].z, ea.z, acc[OKv[m]].z);
      acc[OKv[m]].w = fmaf(X[OLv[m]].w, ea.w, acc[OKv[m]].w);
    }
    // ---- pack hi/lo bf16, write in A-fragment order (row = 2k+h) ----
    #pragma unroll
    for (int k = 0; k < 8; ++k) {
      const float4 a = acc[k];
      const unsigned hx = bf16_rne_hi(a.x), hy = bf16_rne_hi(a.y);
      const unsigned hz = bf16_rne_hi(a.z), hw = bf16_rne_hi(a.w);
      const float rx = a.x - __uint_as_float(hx), ry = a.y - __uint_as_float(hy);
      const float rz = a.z - __uint_as_float(hz), rw = a.w - __uint_as_float(hw);
      const int row = 2 * k + h;
      const int gb = (wv * 4 + tq) * 64 + row * 4 + qq;   // plane-0 granule
      f2[gb * 2 + pp] = make_uint2((hx >> 16) | hy, (hz >> 16) | hw);
      f2[(1024 + gb) * 2 + pp] =
          make_uint2((bf16_rne_hi(rx) >> 16) | bf16_rne_hi(ry),
                     (bf16_rne_hi(rz) >> 16) | bf16_rne_hi(rw));
    }
    __syncthreads();   // A-planes complete

    // ---- MFMA: wave computes u0,u0+1 for all 4 M-tiles ----
    floatx4 C[2][4];
    #pragma unroll
    for (int v = 0; v < 2; ++v)
      #pragma unroll
      for (int mt = 0; mt < 4; ++mt) C[v][mt] = (floatx4){0.f, 0.f, 0.f, 0.f};

    #pragma unroll
    for (int t = 0; t < 4; ++t) {
      const uint4* wp0 = wfrag + ((((l * 4 + t) * 8 + u0) * 2) << 6);
      FragU B0h, B0l, B1h, B1l;
      B0h.q = wp0[lane];        B0l.q = wp0[64 + lane];
      B1h.q = wp0[128 + lane];  B1l.q = wp0[192 + lane];
      #pragma unroll
      for (int mt = 0; mt < 4; ++mt) {
        const int gA = (mt * 4 + t) * 64 + m16 * 4 + q2;
        FragU Ah, Al;
        Ah.q = fragbuf[gA];
        Al.q = fragbuf[1024 + gA];
        C[0][mt] = __builtin_amdgcn_mfma_f32_16x16x32_bf16(Ah.v, B0h.v, C[0][mt], 0, 0, 0);
        C[0][mt] = __builtin_amdgcn_mfma_f32_16x16x32_bf16(Al.v, B0h.v, C[0][mt], 0, 0, 0);
        C[0][mt] = __builtin_amdgcn_mfma_f32_16x16x32_bf16(Ah.v, B0l.v, C[0][mt], 0, 0, 0);
        C[1][mt] = __builtin_amdgcn_mfma_f32_16x16x32_bf16(Ah.v, B1h.v, C[1][mt], 0, 0, 0);
        C[1][mt] = __builtin_amdgcn_mfma_f32_16x16x32_bf16(Al.v, B1h.v, C[1][mt], 0, 0, 0);
        C[1][mt] = __builtin_amdgcn_mfma_f32_16x16x32_bf16(Ah.v, B1l.v, C[1][mt], 0, 0, 0);
      }
    }
    __syncthreads();   // all A-frag reads done; fragbuf reusable as epi

    // ---- epilogue: C (row=q2*4+r, ch=u*16+m16) -> epi -> flat update ----
    #pragma unroll
    for (int v = 0; v < 2; ++v)
      #pragma unroll
      for (int mt = 0; mt < 4; ++mt)
        #pragma unroll
        for (int r = 0; r < 4; ++r) {
          const int row = mt * 16 + q2 * 4 + r;
          const int cs  = ((u0 + v) * 16 + m16) ^ ((q2 & 1) << 4); // (row>>2)&1 == q2&1
          epi[row * 128 + cs] = C[v][mt][r];
        }
    __syncthreads();
    const float4 b4 = ld4(b_conv + l * EMB + c0);
    #pragma unroll
    for (int k = 0; k < 8; ++k) {
      const int row = wv * 16 + 2 * k + h;
      const int cs  = c0 ^ ((((2 * k + h) >> 2) & 1) << 4);
      const float4 o = *(const float4*)(epi + row * 128 + cs);
      X[k].x += fmaxf(o.x + b4.x, 0.f);
      X[k].y += fmaxf(o.y + b4.y, 0.f);
      X[k].z += fmaxf(o.z + b4.z, 0.f);
      X[k].w += fmaxf(o.w + b4.w, 0.f);
    }
    __syncthreads();   // epi reads done before next layer's A-writes
  }

  // ---- pooling: max over k, dot w_pred, per-graph atomic sum ----
  float4 pv = X[0];
  #pragma unroll
  for (int k = 1; k < 8; ++k) {
    pv.x = fmaxf(pv.x, X[k].x);
    pv.y = fmaxf(pv.y, X[k].y);
    pv.z = fmaxf(pv.z, X[k].z);
    pv.w = fmaxf(pv.w, X[k].w);
  }
  const float4 wp = ld4(w_pred + c0);
  float s = pv.x * wp.x + pv.y * wp.y + pv.z * wp.z + pv.w * wp.w;
  #pragma unroll
  for (int off = 16; off; off >>= 1) s += __shfl_xor(s, off, 64);
  if (l5 == 0) atomicAdd(out + g, s);
}

extern "C" void kernel_launch(void* const* d_in, const int* in_sizes, int n_in,
                              void* d_out, int out_size, void* d_ws, size_t ws_size,
                              hipStream_t stream) {
  const int*   x         = (const int*)d_in[0];
  const int*   edge_attr = (const int*)d_in[1];
  const int*   tuplefeat = (const int*)d_in[2];
  const float* emb_x     = (const float*)d_in[12];
  const float* emb_ea    = (const float*)d_in[13];
  const float* emb_tf    = (const float*)d_in[14];
  const float* w_ti      = (const float*)d_in[15];
  const float* b_ti      = (const float*)d_in[16];
  const float* w_conv    = (const float*)d_in[17];
  const float* b_conv    = (const float*)d_in[18];
  const float* w_pred    = (const float*)d_in[19];
  const float* b_pred    = (const float*)d_in[20];
  float* out = (float*)d_out;
  float* lin32 = (float*)d_ws;                               // 32*128 fp32 = 16 KB
  uint4* wfrag = (uint4*)((char*)d_ws + 32 * EMB * 4);       // 320 KB B-fragments

  hipLaunchKernelGGL(out_init_kernel, dim3(1), dim3(64), 0, stream, out, b_pred);
  hipLaunchKernelGGL(lin_kernel, dim3(32), dim3(EMB), 0, stream, emb_x, w_ti, b_ti, lin32);
  hipLaunchKernelGGL(wfrag_kernel, dim3(80), dim3(256), 0, stream, w_conv, wfrag);
  hipLaunchKernelGGL(i2gnn_mfma, dim3(4096), dim3(256), 0, stream,
                     x, edge_attr, tuplefeat, emb_x, emb_tf, emb_ea, lin32,
                     b_conv, w_pred, wfrag, out);
}